// Round 6
// baseline (1187.414 us; speedup 1.0000x reference)
//
#include <hip/hip_runtime.h>
#include <hip/hip_bf16.h>
#include <math.h>

#define N_NODES 20000
#define N_EDGES 480000
#define HIDDEN  128
#define ZDIM    384        // 2*HIDDEN + EDGE_FEAT
#define NOUT    256        // 2*HIDDEN
#define BN_EPS  1e-5f
#define NTILES  (N_EDGES / 64)
#define PGRID   512        // persistent blocks: 2 per CU

#define LDA 392            // A-tile row stride (bf16), 784B -> ~2-way banks (free)
#define LDZ 264            // z-transpose tile stride

using bf16x8 = __attribute__((ext_vector_type(8))) short;
using f32x4  = __attribute__((ext_vector_type(4))) float;
using s16x4  = __attribute__((ext_vector_type(4))) short;

struct f32x8 { float4 a, b; };

__device__ __forceinline__ unsigned short f2b(float f) {
    union { float f; unsigned u; } v; v.f = f;
    unsigned r = v.u + 0x7fffu + ((v.u >> 16) & 1u);   // RTNE
    return (unsigned short)(r >> 16);
}
__device__ __forceinline__ float bflo(unsigned u) {
    union { unsigned x; float f; } v; v.x = u << 16; return v.f;
}
__device__ __forceinline__ float bfhi(unsigned u) {
    union { unsigned x; float f; } v; v.x = u & 0xffff0000u; return v.f;
}
__device__ __forceinline__ float b2f(unsigned short s) {
    union { unsigned u; float f; } v; v.u = ((unsigned)s) << 16; return v.f;
}
__device__ __forceinline__ float sigmoid_(float x) {
    return 1.f / (1.f + __expf(-x));
}
__device__ __forceinline__ float softplus_(float x) {
    return fmaxf(x, 0.f) + __logf(1.f + __expf(-fabsf(x)));
}
__device__ __forceinline__ f32x8 ld8(const float* p) {
    f32x8 r; r.a = *(const float4*)p; r.b = *(const float4*)(p + 4); return r;
}
__device__ __forceinline__ bf16x8 cvt8(f32x8 v) {
    bf16x8 pk;
    pk[0] = (short)f2b(v.a.x); pk[1] = (short)f2b(v.a.y);
    pk[2] = (short)f2b(v.a.z); pk[3] = (short)f2b(v.a.w);
    pk[4] = (short)f2b(v.b.x); pk[5] = (short)f2b(v.b.y);
    pk[6] = (short)f2b(v.b.z); pk[7] = (short)f2b(v.b.w);
    return pk;
}
// gather source pointer for staging chunk u (0..3071) of tile starting at row0
__device__ __forceinline__ const float* aSrc(int u, int row0,
        const float* __restrict__ h, const float* __restrict__ e,
        const int* __restrict__ src, const int* __restrict__ dst) {
    int r  = u / 48;
    int f0 = (u - r * 48) * 8;
    int row = row0 + r;
    if (f0 < 128)  return h + (size_t)src[row] * HIDDEN + f0;
    if (f0 < 256)  return h + (size_t)dst[row] * HIDDEN + (f0 - 128);
    return e + (size_t)row * HIDDEN + (f0 - 256);
}

// ---- W [384][256] f32  ->  Wt [256][384] bf16 ----------------------------
__global__ void convW(const float* __restrict__ W, short* __restrict__ wt) {
    int n = blockIdx.x;
    for (int k = threadIdx.x; k < ZDIM; k += 256)
        wt[n * ZDIM + k] = (short)f2b(W[(size_t)k * NOUT + n]);
}

// ---- BN stats -> scale/shift ---------------------------------------------
__global__ void bn_finalize(const float* __restrict__ stats,
                            const float* __restrict__ gamma,
                            const float* __restrict__ beta,
                            float* __restrict__ scaleC,
                            float* __restrict__ shiftC) {
    int c = threadIdx.x;
    float s = 0.f, q = 0.f;
    for (int p = 0; p < 64; ++p) {
        s += stats[p * 512 + c];
        q += stats[p * 512 + 256 + c];
    }
    const float invE = 1.f / (float)N_EDGES;
    float m   = s * invE;                    // linear bias b cancels in BN
    float var = q * invE - m * m;
    float inv = rsqrtf(var + BN_EPS);
    float sc  = gamma[c] * inv;
    scaleC[c] = sc;
    shiftC[c] = beta[c] - m * sc;
}

// ---- counting sort of edges by dst ---------------------------------------
__global__ void hist_dst(const int* __restrict__ dst, int* __restrict__ counts) {
    int i = blockIdx.x * 256 + threadIdx.x;
    if (i < N_EDGES) atomicAdd(&counts[dst[i]], 1);
}

__global__ void scan_nodes(const int* __restrict__ counts, int* __restrict__ offs,
                           int* __restrict__ cursor) {
    __shared__ int part[1024];
    int t = threadIdx.x;
    int base = t * 20;
    int local[20]; int s = 0;
    #pragma unroll
    for (int k = 0; k < 20; ++k) {
        int idx = base + k;
        int v = (idx < N_NODES) ? counts[idx] : 0;
        local[k] = s; s += v;
    }
    part[t] = s; __syncthreads();
    for (int d = 1; d < 1024; d <<= 1) {
        int v = (t >= d) ? part[t - d] : 0;
        __syncthreads();
        part[t] += v;
        __syncthreads();
    }
    int pre = (t > 0) ? part[t - 1] : 0;
    #pragma unroll
    for (int k = 0; k < 20; ++k) {
        int idx = base + k;
        if (idx < N_NODES) { int o = pre + local[k]; offs[idx] = o; cursor[idx] = o; }
    }
}

__global__ void build_perm(const int* __restrict__ dst, int* __restrict__ cursor,
                           int* __restrict__ perm) {
    int i = blockIdx.x * 256 + threadIdx.x;
    if (i < N_EDGES) { int p = atomicAdd(&cursor[dst[i]], 1); perm[p] = i; }
}

// ---- persistent, cross-tile-pipelined edge GEMM (stats + raw-z write) ----
__global__ __launch_bounds__(256, 2)
void edge_gemm_p(const float* __restrict__ h, const float* __restrict__ e,
                 const int* __restrict__ src, const int* __restrict__ dst,
                 const short* __restrict__ wt,
                 float* __restrict__ stats, short* __restrict__ zout) {
    const int tid  = threadIdx.x;
    const int lane = tid & 63;
    const int brow = lane & 15;
    const int kgo  = (lane >> 4) * 8;
    const int wcol = (tid >> 6) * 64;

    __shared__ __align__(16) short lds[64 * LDA];   // 50176 B; z-tile reuses it

    const short* wB[4];
    #pragma unroll
    for (int n = 0; n < 4; ++n)
        wB[n] = wt + (size_t)(wcol + n * 16 + brow) * ZDIM + kgo;

    float sreg[4] = {0.f, 0.f, 0.f, 0.f};
    float qreg[4] = {0.f, 0.f, 0.f, 0.f};

    f32x8  ldA[6], ldB[6];
    bf16x8 stA[6], stB[6];

    // ---- prologue: stage tile t0 ----
    const int t0 = blockIdx.x;
    {
        const int row0 = t0 * 64;
        #pragma unroll
        for (int j = 0; j < 6; ++j) ldA[j] = ld8(aSrc(tid + j * 256, row0, h, e, src, dst));
        #pragma unroll
        for (int j = 0; j < 6; ++j) ldB[j] = ld8(aSrc(tid + (j + 6) * 256, row0, h, e, src, dst));
        #pragma unroll
        for (int j = 0; j < 6; ++j) { stA[j] = cvt8(ldA[j]); stB[j] = cvt8(ldB[j]); }
        #pragma unroll
        for (int j = 0; j < 12; ++j) {
            int u = tid + j * 256;
            int r = u / 48;
            int f0 = (u - r * 48) * 8;
            *(bf16x8*)&lds[r * LDA + f0] = (j < 6) ? stA[j] : stB[j - 6];
        }
        __syncthreads();
    }

    for (int t = t0; t < NTILES; t += PGRID) {
        const int  tn   = t + PGRID;
        const bool nx   = tn < NTILES;
        const int  rown = tn * 64;

        // ---- K loop over staged tile; issue next tile's loads inside ----
        f32x4 acc[4][4] = {};
        bf16x8 bC[4];
        #pragma unroll
        for (int n = 0; n < 4; ++n) bC[n] = *(const bf16x8*)(wB[n]);

        #pragma unroll
        for (int kk = 0; kk < 12; ++kk) {
            if (kk == 0 && nx) {
                #pragma unroll
                for (int j = 0; j < 6; ++j)
                    ldA[j] = ld8(aSrc(tid + j * 256, rown, h, e, src, dst));
            }
            if (kk == 4 && nx) {
                #pragma unroll
                for (int j = 0; j < 6; ++j) stA[j] = cvt8(ldA[j]);
            }
            if (kk == 8 && nx) {
                #pragma unroll
                for (int j = 0; j < 6; ++j)
                    ldB[j] = ld8(aSrc(tid + (j + 6) * 256, rown, h, e, src, dst));
            }
            bf16x8 aC[4];
            #pragma unroll
            for (int m = 0; m < 4; ++m)
                aC[m] = *(const bf16x8*)&lds[(m * 16 + brow) * LDA + kk * 32 + kgo];
            bf16x8 bN[4];
            if (kk < 11) {
                #pragma unroll
                for (int n = 0; n < 4; ++n)
                    bN[n] = *(const bf16x8*)(wB[n] + (kk + 1) * 32);
            }
            #pragma unroll
            for (int m = 0; m < 4; ++m)
                #pragma unroll
                for (int n = 0; n < 4; ++n)
                    acc[m][n] = __builtin_amdgcn_mfma_f32_16x16x32_bf16(
                                    aC[m], bC[n], acc[m][n], 0, 0, 0);
            if (kk < 11) {
                #pragma unroll
                for (int n = 0; n < 4; ++n) bC[n] = bN[n];
            }
        }

        // ---- stats into registers (flushed once per block) ----
        #pragma unroll
        for (int n = 0; n < 4; ++n)
            #pragma unroll
            for (int m = 0; m < 4; ++m)
                #pragma unroll
                for (int r = 0; r < 4; ++r) {
                    float v = acc[m][n][r];
                    sreg[n] += v; qreg[n] += v * v;
                }

        __syncthreads();                       // all waves done reading A(t)

        // ---- z transpose into LDS ----
        #pragma unroll
        for (int m = 0; m < 4; ++m) {
            int rowb = m * 16 + (lane >> 4) * 4;
            #pragma unroll
            for (int n = 0; n < 4; ++n) {
                int col = wcol + n * 16 + brow;
                #pragma unroll
                for (int r = 0; r < 4; ++r)
                    lds[(rowb + r) * LDZ + col] = (short)f2b(acc[m][n][r]);
            }
        }
        __syncthreads();

        // ---- coalesced z store; cvt batch B meanwhile ----
        const size_t zb = (size_t)t * 64 * NOUT;
        #pragma unroll
        for (int it = 0; it < 8; ++it) {
            int chunk = tid + it * 256;
            int r = chunk >> 5;
            int c = (chunk & 31) * 8;
            *(bf16x8*)&zout[zb + (size_t)r * NOUT + c] = *(const bf16x8*)&lds[r * LDZ + c];
        }
        if (nx) {
            #pragma unroll
            for (int j = 0; j < 6; ++j) stB[j] = cvt8(ldB[j]);
        }
        __syncthreads();                       // z LDS reads complete

        // ---- stage next tile into LDS ----
        if (nx) {
            #pragma unroll
            for (int j = 0; j < 12; ++j) {
                int u = tid + j * 256;
                int r = u / 48;
                int f0 = (u - r * 48) * 8;
                *(bf16x8*)&lds[r * LDA + f0] = (j < 6) ? stA[j] : stB[j - 6];
            }
        }
        __syncthreads();
    }

    // ---- flush stats ----
    float* base = stats + (size_t)(blockIdx.x & 63) * 512;
    #pragma unroll
    for (int n = 0; n < 4; ++n) {
        float s = sreg[n], q = qreg[n];
        s += __shfl_xor(s, 16, 64); s += __shfl_xor(s, 32, 64);
        q += __shfl_xor(q, 16, 64); q += __shfl_xor(q, 32, 64);
        if (lane < 16) {
            int col = wcol + n * 16 + lane;
            atomicAdd(base + col, s);
            atomicAdd(base + 256 + col, q);
        }
    }
}

// ---- fallback (small ws): stage-all-LDS GEMM, stats or scatter -----------
template<int MODE>   // 1: stats only   2: normalize+gate+atomic scatter
__global__ __launch_bounds__(256)
void edge_gemm_fb(const float* __restrict__ h, const float* __restrict__ e,
                  const int* __restrict__ src, const int* __restrict__ dst,
                  const short* __restrict__ wt,
                  float* __restrict__ stats,
                  const float* __restrict__ scaleC, const float* __restrict__ shiftC,
                  float* __restrict__ agg) {
    const int tid  = threadIdx.x;
    const int bm   = blockIdx.x;
    const int rowBase = bm * 64;
    const int lane = tid & 63;
    const int brow = lane & 15;
    const int kgo  = (lane >> 4) * 8;
    const int wcol = (tid >> 6) * 64;

    __shared__ __align__(16) short lds[64 * LDA];

    #pragma unroll
    for (int j = 0; j < 12; ++j) {
        int u = tid + j * 256;
        int r = u / 48;
        int f0 = (u - r * 48) * 8;
        *(bf16x8*)&lds[r * LDA + f0] = cvt8(ld8(aSrc(u, rowBase, h, e, src, dst)));
    }
    __syncthreads();

    const short* wB[4];
    #pragma unroll
    for (int n = 0; n < 4; ++n)
        wB[n] = wt + (size_t)(wcol + n * 16 + brow) * ZDIM + kgo;

    f32x4 acc[4][4] = {};
    #pragma unroll
    for (int kk = 0; kk < 12; ++kk) {
        bf16x8 aC[4], bC[4];
        #pragma unroll
        for (int m = 0; m < 4; ++m)
            aC[m] = *(const bf16x8*)&lds[(m * 16 + brow) * LDA + kk * 32 + kgo];
        #pragma unroll
        for (int n = 0; n < 4; ++n) bC[n] = *(const bf16x8*)(wB[n] + kk * 32);
        #pragma unroll
        for (int m = 0; m < 4; ++m)
            #pragma unroll
            for (int n = 0; n < 4; ++n)
                acc[m][n] = __builtin_amdgcn_mfma_f32_16x16x32_bf16(
                                aC[m], bC[n], acc[m][n], 0, 0, 0);
    }

    if (MODE == 1) {
        float* base = stats + (size_t)(bm & 63) * 512;
        #pragma unroll
        for (int n = 0; n < 4; ++n) {
            float s = 0.f, q = 0.f;
            #pragma unroll
            for (int m = 0; m < 4; ++m)
                #pragma unroll
                for (int r = 0; r < 4; ++r) {
                    float v = acc[m][n][r]; s += v; q += v * v;
                }
            s += __shfl_xor(s, 16, 64); s += __shfl_xor(s, 32, 64);
            q += __shfl_xor(q, 16, 64); q += __shfl_xor(q, 32, 64);
            if (lane < 16) {
                int col = wcol + n * 16 + lane;
                atomicAdd(base + col, s);
                atomicAdd(base + 256 + col, q);
            }
        }
    } else {
        float sc[4], sh[4];
        #pragma unroll
        for (int n = 0; n < 4; ++n) {
            int col = wcol + n * 16 + brow;
            sc[n] = scaleC[col]; sh[n] = shiftC[col];
        }
        __syncthreads();
        #pragma unroll
        for (int m = 0; m < 4; ++m) {
            int rowb = m * 16 + (lane >> 4) * 4;
            #pragma unroll
            for (int n = 0; n < 4; ++n) {
                int col = wcol + n * 16 + brow;
                #pragma unroll
                for (int r = 0; r < 4; ++r)
                    lds[(rowb + r) * LDZ + col] = (short)f2b(acc[m][n][r] * sc[n] + sh[n]);
            }
        }
        __syncthreads();
        const int c0 = (tid & 31) * 4;
        const int r0 = tid >> 5;
        #pragma unroll
        for (int rp = 0; rp < 8; ++rp) {
            int row = rp * 8 + r0;
            int d   = dst[rowBase + row];
            float* ap = agg + (size_t)d * HIDDEN + c0;
            s16x4 f4 = *(const s16x4*)&lds[row * LDZ + c0];
            s16x4 c4 = *(const s16x4*)&lds[row * LDZ + 128 + c0];
            #pragma unroll
            for (int j = 0; j < 4; ++j)
                atomicAdd(ap + j, sigmoid_(b2f((unsigned short)f4[j])) *
                                  softplus_(b2f((unsigned short)c4[j])));
        }
    }
}

// ---- per-node gather-reduce: normalize + gate + segment-sum + residual ----
__global__ __launch_bounds__(256)
void node_gather(const short* __restrict__ z, const int* __restrict__ perm,
                 const int* __restrict__ offs, const int* __restrict__ counts,
                 const float* __restrict__ scaleC, const float* __restrict__ shiftC,
                 const float* __restrict__ h, float* __restrict__ out) {
    int node = blockIdx.x * 4 + (threadIdx.x >> 6);
    int lane = threadIdx.x & 63;
    int l32  = lane & 31;
    int c0   = l32 * 4;

    float scF[4], shF[4], scS[4], shS[4];
    #pragma unroll
    for (int k = 0; k < 4; ++k) {
        scF[k] = scaleC[c0 + k];       shF[k] = shiftC[c0 + k];
        scS[k] = scaleC[128 + c0 + k]; shS[k] = shiftC[128 + c0 + k];
    }

    int s   = offs[node];
    int deg = counts[node];
    float a0 = 0.f, a1 = 0.f, a2 = 0.f, a3 = 0.f;

    for (int j = (lane >> 5); j < deg; j += 4) {
        int jB = j + 2;
        bool hasB = (jB < deg);
        int eA = perm[s + j];
        int eB = hasB ? perm[s + jB] : eA;
        const short* zA = z + (size_t)eA * NOUT + c0;
        const short* zB = z + (size_t)eB * NOUT + c0;
        uint2 fA = *(const uint2*)zA;
        uint2 cA = *(const uint2*)(zA + 128);
        uint2 fB = *(const uint2*)zB;
        uint2 cB = *(const uint2*)(zB + 128);

        float f0 = bflo(fA.x) * scF[0] + shF[0];
        float f1 = bfhi(fA.x) * scF[1] + shF[1];
        float f2 = bflo(fA.y) * scF[2] + shF[2];
        float f3 = bfhi(fA.y) * scF[3] + shF[3];
        float g0 = bflo(cA.x) * scS[0] + shS[0];
        float g1 = bfhi(cA.x) * scS[1] + shS[1];
        float g2 = bflo(cA.y) * scS[2] + shS[2];
        float g3 = bfhi(cA.y) * scS[3] + shS[3];
        a0 += sigmoid_(f0) * softplus_(g0);
        a1 += sigmoid_(f1) * softplus_(g1);
        a2 += sigmoid_(f2) * softplus_(g2);
        a3 += sigmoid_(f3) * softplus_(g3);

        if (hasB) {
            f0 = bflo(fB.x) * scF[0] + shF[0];
            f1 = bfhi(fB.x) * scF[1] + shF[1];
            f2 = bflo(fB.y) * scF[2] + shF[2];
            f3 = bfhi(fB.y) * scF[3] + shF[3];
            g0 = bflo(cB.x) * scS[0] + shS[0];
            g1 = bfhi(cB.x) * scS[1] + shS[1];
            g2 = bflo(cB.y) * scS[2] + shS[2];
            g3 = bfhi(cB.y) * scS[3] + shS[3];
            a0 += sigmoid_(f0) * softplus_(g0);
            a1 += sigmoid_(f1) * softplus_(g1);
            a2 += sigmoid_(f2) * softplus_(g2);
            a3 += sigmoid_(f3) * softplus_(g3);
        }
    }
    a0 += __shfl_xor(a0, 32, 64);
    a1 += __shfl_xor(a1, 32, 64);
    a2 += __shfl_xor(a2, 32, 64);
    a3 += __shfl_xor(a3, 32, 64);

    if (lane < 32) {
        size_t o = (size_t)node * HIDDEN + c0;
        float4 hv = *(const float4*)&h[o];
        float4 r;
        r.x = softplus_(hv.x + a0);
        r.y = softplus_(hv.y + a1);
        r.z = softplus_(hv.z + a2);
        r.w = softplus_(hv.w + a3);
        *(float4*)&out[o] = r;
    }
}

// ---- fallback finalize ----------------------------------------------------
__global__ void node_finalize(const float* __restrict__ h, float* __restrict__ out) {
    int i = blockIdx.x * 256 + threadIdx.x;
    float4 hv = ((const float4*)h)[i];
    float4 av = ((float4*)out)[i];
    float4 r;
    r.x = softplus_(hv.x + av.x);
    r.y = softplus_(hv.y + av.y);
    r.z = softplus_(hv.z + av.z);
    r.w = softplus_(hv.w + av.w);
    ((float4*)out)[i] = r;
}

extern "C" void kernel_launch(void* const* d_in, const int* in_sizes, int n_in,
                              void* d_out, int out_size, void* d_ws, size_t ws_size,
                              hipStream_t stream) {
    const float* h     = (const float*)d_in[0];
    const float* e     = (const float*)d_in[1];
    const int*   srcp  = (const int*)d_in[2];
    const int*   dstp  = (const int*)d_in[3];
    const float* W     = (const float*)d_in[4];
    // d_in[5] = b : cancels through BatchNorm
    const float* gamma = (const float*)d_in[6];
    const float* beta  = (const float*)d_in[7];
    float* out = (float*)d_out;

    char*  ws     = (char*)d_ws;
    float* stats  = (float*)ws;                  // 64*512*4 = 131072 B
    float* scaleC = (float*)(ws + 131072);
    float* shiftC = (float*)(ws + 132096);
    short* wt     = (short*)(ws + 133120);       // 196608 B -> 329728
    int*   counts = (int*)(ws + 329728);
    int*   offs   = (int*)(ws + 409856);
    int*   cursor = (int*)(ws + 489984);
    int*   perm   = (int*)(ws + 570112);         // 1.92 MB -> 2490112
    short* zbuf   = (short*)(ws + 2490112);      // 245.76 MB
    const size_t need = 2490112ull + (size_t)N_EDGES * NOUT * 2;

    hipMemsetAsync(stats, 0, 131072, stream);
    convW<<<NOUT, 256, 0, stream>>>(W, wt);

    if (ws_size >= need) {
        hipMemsetAsync(counts, 0, N_NODES * sizeof(int), stream);
        hist_dst<<<(N_EDGES + 255) / 256, 256, 0, stream>>>(dstp, counts);
        scan_nodes<<<1, 1024, 0, stream>>>(counts, offs, cursor);
        build_perm<<<(N_EDGES + 255) / 256, 256, 0, stream>>>(dstp, cursor, perm);

        edge_gemm_p<<<PGRID, 256, 0, stream>>>(h, e, srcp, dstp, wt, stats, zbuf);
        bn_finalize<<<1, 256, 0, stream>>>(stats, gamma, beta, scaleC, shiftC);
        node_gather<<<N_NODES / 4, 256, 0, stream>>>(zbuf, perm, offs, counts,
                scaleC, shiftC, h, out);
    } else {
        hipMemsetAsync(out, 0, (size_t)N_NODES * HIDDEN * sizeof(float), stream);
        edge_gemm_fb<1><<<N_EDGES / 64, 256, 0, stream>>>(h, e, srcp, dstp, wt,
                stats, nullptr, nullptr, nullptr);
        bn_finalize<<<1, 256, 0, stream>>>(stats, gamma, beta, scaleC, shiftC);
        edge_gemm_fb<2><<<N_EDGES / 64, 256, 0, stream>>>(h, e, srcp, dstp, wt,
                stats, scaleC, shiftC, out);
        node_finalize<<<N_NODES * HIDDEN / (4 * 256), 256, 0, stream>>>(h, out);
    }
}

// Round 7
// 564.688 us; speedup vs baseline: 2.1028x; 2.1028x over previous
//
#include <hip/hip_runtime.h>
#include <hip/hip_bf16.h>
#include <math.h>

#define N_NODES 20000
#define N_EDGES 480000
#define HIDDEN  128
#define ZDIM    384        // 2*HIDDEN + EDGE_FEAT
#define NOUT    256        // 2*HIDDEN
#define BN_EPS  1e-5f

#define KH      192        // K staged per half
#define LDA2    200        // 192 + 8 pad (bf16): row stride 400B -> ~2-way banks
#define LDZH    136        // 128 + 8 pad for z col-half transpose tile
#define LDA     392        // fallback kernel only
#define LDZ     264        // fallback kernel only

using bf16x8 = __attribute__((ext_vector_type(8))) short;
using f32x4  = __attribute__((ext_vector_type(4))) float;
using s16x4  = __attribute__((ext_vector_type(4))) short;

struct f32x8 { float4 a, b; };

__device__ __forceinline__ unsigned short f2b(float f) {
    union { float f; unsigned u; } v; v.f = f;
    unsigned r = v.u + 0x7fffu + ((v.u >> 16) & 1u);   // RTNE
    return (unsigned short)(r >> 16);
}
__device__ __forceinline__ float bflo(unsigned u) {
    union { unsigned x; float f; } v; v.x = u << 16; return v.f;
}
__device__ __forceinline__ float bfhi(unsigned u) {
    union { unsigned x; float f; } v; v.x = u & 0xffff0000u; return v.f;
}
__device__ __forceinline__ float b2f(unsigned short s) {
    union { unsigned u; float f; } v; v.u = ((unsigned)s) << 16; return v.f;
}
__device__ __forceinline__ float sigmoid_(float x) {
    return 1.f / (1.f + __expf(-x));
}
__device__ __forceinline__ float softplus_(float x) {
    return fmaxf(x, 0.f) + __logf(1.f + __expf(-fabsf(x)));
}
__device__ __forceinline__ f32x8 ld8(const float* p) {
    f32x8 r; r.a = *(const float4*)p; r.b = *(const float4*)(p + 4); return r;
}
__device__ __forceinline__ bf16x8 cvt8(f32x8 v) {
    bf16x8 pk;
    pk[0] = (short)f2b(v.a.x); pk[1] = (short)f2b(v.a.y);
    pk[2] = (short)f2b(v.a.z); pk[3] = (short)f2b(v.a.w);
    pk[4] = (short)f2b(v.b.x); pk[5] = (short)f2b(v.b.y);
    pk[6] = (short)f2b(v.b.z); pk[7] = (short)f2b(v.b.w);
    return pk;
}

// ---- W [384][256] f32  ->  Wt [256][384] bf16 ----------------------------
__global__ void convW(const float* __restrict__ W, short* __restrict__ wt) {
    int n = blockIdx.x;
    for (int k = threadIdx.x; k < ZDIM; k += 256)
        wt[n * ZDIM + k] = (short)f2b(W[(size_t)k * NOUT + n]);
}

// ---- BN stats -> scale/shift ---------------------------------------------
__global__ void bn_finalize(const float* __restrict__ stats,
                            const float* __restrict__ gamma,
                            const float* __restrict__ beta,
                            float* __restrict__ scaleC,
                            float* __restrict__ shiftC) {
    int c = threadIdx.x;
    float s = 0.f, q = 0.f;
    for (int p = 0; p < 64; ++p) {
        s += stats[p * 512 + c];
        q += stats[p * 512 + 256 + c];
    }
    const float invE = 1.f / (float)N_EDGES;
    float m   = s * invE;                    // linear bias b cancels in BN
    float var = q * invE - m * m;
    float inv = rsqrtf(var + BN_EPS);
    float sc  = gamma[c] * inv;
    scaleC[c] = sc;
    shiftC[c] = beta[c] - m * sc;
}

// ---- counting sort of edges by dst ---------------------------------------
__global__ void hist_dst(const int* __restrict__ dst, int* __restrict__ counts) {
    int i = blockIdx.x * 256 + threadIdx.x;
    if (i < N_EDGES) atomicAdd(&counts[dst[i]], 1);
}

__global__ void scan_nodes(const int* __restrict__ counts, int* __restrict__ offs,
                           int* __restrict__ cursor) {
    __shared__ int part[1024];
    int t = threadIdx.x;
    int base = t * 20;
    int local[20]; int s = 0;
    #pragma unroll
    for (int k = 0; k < 20; ++k) {
        int idx = base + k;
        int v = (idx < N_NODES) ? counts[idx] : 0;
        local[k] = s; s += v;
    }
    part[t] = s; __syncthreads();
    for (int d = 1; d < 1024; d <<= 1) {
        int v = (t >= d) ? part[t - d] : 0;
        __syncthreads();
        part[t] += v;
        __syncthreads();
    }
    int pre = (t > 0) ? part[t - 1] : 0;
    #pragma unroll
    for (int k = 0; k < 20; ++k) {
        int idx = base + k;
        if (idx < N_NODES) { int o = pre + local[k]; offs[idx] = o; cursor[idx] = o; }
    }
}

__global__ void build_perm(const int* __restrict__ dst, int* __restrict__ cursor,
                           int* __restrict__ perm) {
    int i = blockIdx.x * 256 + threadIdx.x;
    if (i < N_EDGES) { int p = atomicAdd(&cursor[dst[i]], 1); perm[p] = i; }
}

// ---- main edge GEMM: half-K staged LDS (25.6 KB) for high residency ------
__global__ __launch_bounds__(256)
void edge_gemm_main(const float* __restrict__ h, const float* __restrict__ e,
                    const int* __restrict__ src, const int* __restrict__ dst,
                    const short* __restrict__ wt,
                    float* __restrict__ stats, short* __restrict__ zout) {
    const int tid  = threadIdx.x;
    const int bm   = blockIdx.x;
    const int rowBase = bm * 64;
    const int lane = tid & 63;
    const int brow = lane & 15;
    const int kgo  = (lane >> 4) * 8;
    const int wv   = tid >> 6;
    const int wcol = wv * 64;

    __shared__ __align__(16) short lds[64 * LDA2];   // 25600 B; zh tile reuses it

    const short* wB[4];
    #pragma unroll
    for (int n = 0; n < 4; ++n)
        wB[n] = wt + (size_t)(wcol + n * 16 + brow) * ZDIM + kgo;

    f32x4 acc[4][4] = {};

    #pragma unroll
    for (int half = 0; half < 2; ++half) {
        // ---- stage 64 x 192 (kabs = half*192 + f0), gathered f32 -> bf16 ----
        #pragma unroll
        for (int j = 0; j < 6; ++j) {
            int u   = tid + j * 256;          // 0..1535 ; 24 chunks per row
            int r   = u / 24;
            int f0  = (u - r * 24) * 8;
            int kabs = half * KH + f0;
            int row = rowBase + r;
            const float* p;
            if (kabs < 128)      p = h + (size_t)src[row] * HIDDEN + kabs;
            else if (kabs < 256) p = h + (size_t)dst[row] * HIDDEN + (kabs - 128);
            else                 p = e + (size_t)row * HIDDEN + (kabs - 256);
            *(bf16x8*)&lds[r * LDA2 + f0] = cvt8(ld8(p));
        }
        __syncthreads();

        // ---- 6 K-steps, 1-deep pipelined ----
        const int kb = half * KH;
        bf16x8 aC[4], bC[4];
        #pragma unroll
        for (int m = 0; m < 4; ++m)
            aC[m] = *(const bf16x8*)&lds[(m * 16 + brow) * LDA2 + kgo];
        #pragma unroll
        for (int n = 0; n < 4; ++n) bC[n] = *(const bf16x8*)(wB[n] + kb);

        #pragma unroll
        for (int kk = 0; kk < 6; ++kk) {
            bf16x8 aN[4], bN[4];
            if (kk < 5) {
                #pragma unroll
                for (int n = 0; n < 4; ++n)
                    bN[n] = *(const bf16x8*)(wB[n] + kb + (kk + 1) * 32);
                #pragma unroll
                for (int m = 0; m < 4; ++m)
                    aN[m] = *(const bf16x8*)&lds[(m * 16 + brow) * LDA2 + (kk + 1) * 32 + kgo];
            }
            #pragma unroll
            for (int m = 0; m < 4; ++m)
                #pragma unroll
                for (int n = 0; n < 4; ++n)
                    acc[m][n] = __builtin_amdgcn_mfma_f32_16x16x32_bf16(
                                    aC[m], bC[n], acc[m][n], 0, 0, 0);
            if (kk < 5) {
                #pragma unroll
                for (int m = 0; m < 4; ++m) aC[m] = aN[m];
                #pragma unroll
                for (int n = 0; n < 4; ++n) bC[n] = bN[n];
            }
        }
        __syncthreads();     // safe to overwrite LDS (restage / z epilogue)
    }

    // ---- stats: per-column sum/sumsq, 64-way-split atomics ----
    {
        float* base = stats + (size_t)(bm & 63) * 512;
        #pragma unroll
        for (int n = 0; n < 4; ++n) {
            float s = 0.f, q = 0.f;
            #pragma unroll
            for (int m = 0; m < 4; ++m)
                #pragma unroll
                for (int r = 0; r < 4; ++r) {
                    float v = acc[m][n][r];
                    s += v; q += v * v;
                }
            s += __shfl_xor(s, 16, 64); s += __shfl_xor(s, 32, 64);
            q += __shfl_xor(q, 16, 64); q += __shfl_xor(q, 32, 64);
            if (lane < 16) {
                int col = wcol + n * 16 + lane;
                atomicAdd(base + col, s);
                atomicAdd(base + 256 + col, q);
            }
        }
    }

    // ---- z epilogue in col-halves (64 x 128 tile each) ----
    #pragma unroll
    for (int zh = 0; zh < 2; ++zh) {
        if ((wv >> 1) == zh) {
            #pragma unroll
            for (int m = 0; m < 4; ++m) {
                int rowb = m * 16 + (lane >> 4) * 4;
                #pragma unroll
                for (int n = 0; n < 4; ++n) {
                    int col = wcol + n * 16 + brow - zh * 128;
                    #pragma unroll
                    for (int r = 0; r < 4; ++r)
                        lds[(rowb + r) * LDZH + col] = (short)f2b(acc[m][n][r]);
                }
            }
        }
        __syncthreads();
        #pragma unroll
        for (int it = 0; it < 4; ++it) {
            int chunk = tid + it * 256;       // 0..1023 ; 16 chunks per row
            int r = chunk >> 4;
            int c = (chunk & 15) * 8;
            *(bf16x8*)&zout[((size_t)rowBase + r) * NOUT + zh * 128 + c] =
                *(const bf16x8*)&lds[r * LDZH + c];
        }
        __syncthreads();
    }
}

// ---- fallback (small ws): stage-all-LDS GEMM, stats or scatter -----------
template<int MODE>   // 1: stats only   2: normalize+gate+atomic scatter
__global__ __launch_bounds__(256)
void edge_gemm_fb(const float* __restrict__ h, const float* __restrict__ e,
                  const int* __restrict__ src, const int* __restrict__ dst,
                  const short* __restrict__ wt,
                  float* __restrict__ stats,
                  const float* __restrict__ scaleC, const float* __restrict__ shiftC,
                  float* __restrict__ agg) {
    const int tid  = threadIdx.x;
    const int bm   = blockIdx.x;
    const int rowBase = bm * 64;
    const int lane = tid & 63;
    const int brow = lane & 15;
    const int kgo  = (lane >> 4) * 8;
    const int wcol = (tid >> 6) * 64;

    __shared__ __align__(16) short lds[64 * LDA];

    #pragma unroll
    for (int j = 0; j < 12; ++j) {
        int u = tid + j * 256;
        int r = u / 48;
        int f0 = (u - r * 48) * 8;
        int row = rowBase + r;
        const float* p;
        if (f0 < 128)      p = h + (size_t)src[row] * HIDDEN + f0;
        else if (f0 < 256) p = h + (size_t)dst[row] * HIDDEN + (f0 - 128);
        else               p = e + (size_t)row * HIDDEN + (f0 - 256);
        *(bf16x8*)&lds[r * LDA + f0] = cvt8(ld8(p));
    }
    __syncthreads();

    const short* wB[4];
    #pragma unroll
    for (int n = 0; n < 4; ++n)
        wB[n] = wt + (size_t)(wcol + n * 16 + brow) * ZDIM + kgo;

    f32x4 acc[4][4] = {};
    #pragma unroll
    for (int kk = 0; kk < 12; ++kk) {
        bf16x8 aC[4], bC[4];
        #pragma unroll
        for (int m = 0; m < 4; ++m)
            aC[m] = *(const bf16x8*)&lds[(m * 16 + brow) * LDA + kk * 32 + kgo];
        #pragma unroll
        for (int n = 0; n < 4; ++n) bC[n] = *(const bf16x8*)(wB[n] + kk * 32);
        #pragma unroll
        for (int m = 0; m < 4; ++m)
            #pragma unroll
            for (int n = 0; n < 4; ++n)
                acc[m][n] = __builtin_amdgcn_mfma_f32_16x16x32_bf16(
                                aC[m], bC[n], acc[m][n], 0, 0, 0);
    }

    if (MODE == 1) {
        float* base = stats + (size_t)(bm & 63) * 512;
        #pragma unroll
        for (int n = 0; n < 4; ++n) {
            float s = 0.f, q = 0.f;
            #pragma unroll
            for (int m = 0; m < 4; ++m)
                #pragma unroll
                for (int r = 0; r < 4; ++r) {
                    float v = acc[m][n][r]; s += v; q += v * v;
                }
            s += __shfl_xor(s, 16, 64); s += __shfl_xor(s, 32, 64);
            q += __shfl_xor(q, 16, 64); q += __shfl_xor(q, 32, 64);
            if (lane < 16) {
                int col = wcol + n * 16 + lane;
                atomicAdd(base + col, s);
                atomicAdd(base + 256 + col, q);
            }
        }
    } else {
        float sc[4], sh[4];
        #pragma unroll
        for (int n = 0; n < 4; ++n) {
            int col = wcol + n * 16 + brow;
            sc[n] = scaleC[col]; sh[n] = shiftC[col];
        }
        __syncthreads();
        #pragma unroll
        for (int m = 0; m < 4; ++m) {
            int rowb = m * 16 + (lane >> 4) * 4;
            #pragma unroll
            for (int n = 0; n < 4; ++n) {
                int col = wcol + n * 16 + brow;
                #pragma unroll
                for (int r = 0; r < 4; ++r)
                    lds[(rowb + r) * LDZ + col] = (short)f2b(acc[m][n][r] * sc[n] + sh[n]);
            }
        }
        __syncthreads();
        const int c0 = (tid & 31) * 4;
        const int r0 = tid >> 5;
        #pragma unroll
        for (int rp = 0; rp < 8; ++rp) {
            int row = rp * 8 + r0;
            int d   = dst[rowBase + row];
            float* ap = agg + (size_t)d * HIDDEN + c0;
            s16x4 f4 = *(const s16x4*)&lds[row * LDZ + c0];
            s16x4 c4 = *(const s16x4*)&lds[row * LDZ + 128 + c0];
            #pragma unroll
            for (int j = 0; j < 4; ++j)
                atomicAdd(ap + j, sigmoid_(b2f((unsigned short)f4[j])) *
                                  softplus_(b2f((unsigned short)c4[j])));
        }
    }
}

// ---- per-node gather-reduce: normalize + gate + segment-sum + residual ----
__global__ __launch_bounds__(256)
void node_gather(const short* __restrict__ z, const int* __restrict__ perm,
                 const int* __restrict__ offs, const int* __restrict__ counts,
                 const float* __restrict__ scaleC, const float* __restrict__ shiftC,
                 const float* __restrict__ h, float* __restrict__ out) {
    int node = blockIdx.x * 4 + (threadIdx.x >> 6);
    int lane = threadIdx.x & 63;
    int l32  = lane & 31;
    int c0   = l32 * 4;

    float scF[4], shF[4], scS[4], shS[4];
    #pragma unroll
    for (int k = 0; k < 4; ++k) {
        scF[k] = scaleC[c0 + k];       shF[k] = shiftC[c0 + k];
        scS[k] = scaleC[128 + c0 + k]; shS[k] = shiftC[128 + c0 + k];
    }

    int s   = offs[node];
    int deg = counts[node];
    float a0 = 0.f, a1 = 0.f, a2 = 0.f, a3 = 0.f;

    for (int j = (lane >> 5); j < deg; j += 4) {
        int jB = j + 2;
        bool hasB = (jB < deg);
        int eA = perm[s + j];
        int eB = hasB ? perm[s + jB] : eA;
        const short* zA = z + (size_t)eA * NOUT + c0;
        const short* zB = z + (size_t)eB * NOUT + c0;
        uint2 fA = *(const uint2*)zA;
        uint2 cA = *(const uint2*)(zA + 128);
        uint2 fB = *(const uint2*)zB;
        uint2 cB = *(const uint2*)(zB + 128);

        float f0 = bflo(fA.x) * scF[0] + shF[0];
        float f1 = bfhi(fA.x) * scF[1] + shF[1];
        float f2 = bflo(fA.y) * scF[2] + shF[2];
        float f3 = bfhi(fA.y) * scF[3] + shF[3];
        float g0 = bflo(cA.x) * scS[0] + shS[0];
        float g1 = bfhi(cA.x) * scS[1] + shS[1];
        float g2 = bflo(cA.y) * scS[2] + shS[2];
        float g3 = bfhi(cA.y) * scS[3] + shS[3];
        a0 += sigmoid_(f0) * softplus_(g0);
        a1 += sigmoid_(f1) * softplus_(g1);
        a2 += sigmoid_(f2) * softplus_(g2);
        a3 += sigmoid_(f3) * softplus_(g3);

        if (hasB) {
            f0 = bflo(fB.x) * scF[0] + shF[0];
            f1 = bfhi(fB.x) * scF[1] + shF[1];
            f2 = bflo(fB.y) * scF[2] + shF[2];
            f3 = bfhi(fB.y) * scF[3] + shF[3];
            g0 = bflo(cB.x) * scS[0] + shS[0];
            g1 = bfhi(cB.x) * scS[1] + shS[1];
            g2 = bflo(cB.y) * scS[2] + shS[2];
            g3 = bfhi(cB.y) * scS[3] + shS[3];
            a0 += sigmoid_(f0) * softplus_(g0);
            a1 += sigmoid_(f1) * softplus_(g1);
            a2 += sigmoid_(f2) * softplus_(g2);
            a3 += sigmoid_(f3) * softplus_(g3);
        }
    }
    a0 += __shfl_xor(a0, 32, 64);
    a1 += __shfl_xor(a1, 32, 64);
    a2 += __shfl_xor(a2, 32, 64);
    a3 += __shfl_xor(a3, 32, 64);

    if (lane < 32) {
        size_t o = (size_t)node * HIDDEN + c0;
        float4 hv = *(const float4*)&h[o];
        float4 r;
        r.x = softplus_(hv.x + a0);
        r.y = softplus_(hv.y + a1);
        r.z = softplus_(hv.z + a2);
        r.w = softplus_(hv.w + a3);
        *(float4*)&out[o] = r;
    }
}

// ---- fallback finalize ----------------------------------------------------
__global__ void node_finalize(const float* __restrict__ h, float* __restrict__ out) {
    int i = blockIdx.x * 256 + threadIdx.x;
    float4 hv = ((const float4*)h)[i];
    float4 av = ((float4*)out)[i];
    float4 r;
    r.x = softplus_(hv.x + av.x);
    r.y = softplus_(hv.y + av.y);
    r.z = softplus_(hv.z + av.z);
    r.w = softplus_(hv.w + av.w);
    ((float4*)out)[i] = r;
}

extern "C" void kernel_launch(void* const* d_in, const int* in_sizes, int n_in,
                              void* d_out, int out_size, void* d_ws, size_t ws_size,
                              hipStream_t stream) {
    const float* h     = (const float*)d_in[0];
    const float* e     = (const float*)d_in[1];
    const int*   srcp  = (const int*)d_in[2];
    const int*   dstp  = (const int*)d_in[3];
    const float* W     = (const float*)d_in[4];
    // d_in[5] = b : cancels through BatchNorm
    const float* gamma = (const float*)d_in[6];
    const float* beta  = (const float*)d_in[7];
    float* out = (float*)d_out;

    char*  ws     = (char*)d_ws;
    float* stats  = (float*)ws;                  // 64*512*4 = 131072 B
    float* scaleC = (float*)(ws + 131072);
    float* shiftC = (float*)(ws + 132096);
    short* wt     = (short*)(ws + 133120);       // 196608 B -> 329728
    int*   counts = (int*)(ws + 329728);
    int*   offs   = (int*)(ws + 409856);
    int*   cursor = (int*)(ws + 489984);
    int*   perm   = (int*)(ws + 570112);         // 1.92 MB -> 2490112
    short* zbuf   = (short*)(ws + 2490112);      // 245.76 MB
    const size_t need = 2490112ull + (size_t)N_EDGES * NOUT * 2;

    hipMemsetAsync(stats, 0, 131072, stream);
    convW<<<NOUT, 256, 0, stream>>>(W, wt);

    if (ws_size >= need) {
        hipMemsetAsync(counts, 0, N_NODES * sizeof(int), stream);
        hist_dst<<<(N_EDGES + 255) / 256, 256, 0, stream>>>(dstp, counts);
        scan_nodes<<<1, 1024, 0, stream>>>(counts, offs, cursor);
        build_perm<<<(N_EDGES + 255) / 256, 256, 0, stream>>>(dstp, cursor, perm);

        edge_gemm_main<<<N_EDGES / 64, 256, 0, stream>>>(h, e, srcp, dstp, wt,
                stats, zbuf);
        bn_finalize<<<1, 256, 0, stream>>>(stats, gamma, beta, scaleC, shiftC);
        node_gather<<<N_NODES / 4, 256, 0, stream>>>(zbuf, perm, offs, counts,
                scaleC, shiftC, h, out);
    } else {
        hipMemsetAsync(out, 0, (size_t)N_NODES * HIDDEN * sizeof(float), stream);
        edge_gemm_fb<1><<<N_EDGES / 64, 256, 0, stream>>>(h, e, srcp, dstp, wt,
                stats, nullptr, nullptr, nullptr);
        bn_finalize<<<1, 256, 0, stream>>>(stats, gamma, beta, scaleC, shiftC);
        edge_gemm_fb<2><<<N_EDGES / 64, 256, 0, stream>>>(h, e, srcp, dstp, wt,
                stats, scaleC, shiftC, out);
        node_finalize<<<N_NODES * HIDDEN / (4 * 256), 256, 0, stream>>>(h, out);
    }
}